// Round 4
// baseline (161.164 us; speedup 1.0000x reference)
//
#include <hip/hip_runtime.h>
#include <cmath>

#define NEG_INF (-1.0e30f)

static constexpr int B = 256;
static constexpr int N = 65536;
static constexpr int CHUNKS = 8;                        // blocks per row
static constexpr int THREADS = 256;                     // 4 waves per block
static constexpr int NBLOCKS = B * CHUNKS;              // 2048
static constexpr int CHUNK_ELEMS = N / CHUNKS;          // 8192
static constexpr int ITER = CHUNK_ELEMS / 4 / THREADS;  // 8 float4 per thread per array
static constexpr float C_OFF = 40.96f;                  // 64*0.8^2, upper bound of both logits
static constexpr float CAND_THRESH = 0.98f;
static constexpr int CAP = 512;                         // LDS candidate capacity (mean ~41/block)
static constexpr int PSTRIDE = 16;                      // floats per block partial

__device__ __forceinline__ float wave_sum_f(float v) {
#pragma unroll
  for (int off = 32; off >= 1; off >>= 1) v += __shfl_xor(v, off, 64);
  return v;
}
__device__ __forceinline__ int wave_sum_i(int v) {
#pragma unroll
  for (int off = 32; off >= 1; off >>= 1) v += __shfl_xor(v, off, 64);
  return v;
}
__device__ __forceinline__ int wave_max_i(int v) {
#pragma unroll
  for (int off = 32; off >= 1; off >>= 1) v = max(v, __shfl_xor(v, off, 64));
  return v;
}

// sorted-descending top-10 insert into t[0..9] (t[10..15] pad)
__device__ __forceinline__ void insert10(float t[16], float s) {
  if (s > t[9]) {
    t[9] = s;
#pragma unroll
    for (int i = 9; i > 0; --i) {
      float a = t[i - 1], b = t[i];
      t[i - 1] = fmaxf(a, b);
      t[i] = fminf(a, b);
    }
  }
}

// Merge this lane's descending-sorted 16-list with XOR-partner lane's list,
// keeping top-16 of the union (bitonic top-k merge).
__device__ __forceinline__ void merge_lists_shfl(float t[16], int off) {
  float b[16];
#pragma unroll
  for (int i = 0; i < 16; ++i) b[i] = __shfl_xor(t[i], off, 64);
  float c[16];
#pragma unroll
  for (int i = 0; i < 16; ++i) c[i] = fmaxf(t[i], b[15 - i]);
#pragma unroll
  for (int s = 8; s >= 1; s >>= 1) {
#pragma unroll
    for (int i = 0; i < 16; ++i) {
      if ((i & s) == 0) {
        float lo = c[i], hi = c[i + s];
        c[i] = fmaxf(lo, hi);
        c[i + s] = fminf(lo, hi);
      }
    }
  }
#pragma unroll
  for (int i = 0; i < 16; ++i) t[i] = c[i];
}

// Hot-loop per element: fully branchless straight-line code.
__device__ __forceinline__ void proc(float s, float l, float& s_p, float& s_n,
                                     int& nn, int& cc, float c4[4]) {
  const bool pos = l > 0.5f;
  const bool neg = l < 0.25f;
  float d = pos ? (0.8f - s) : (s - 0.2f);
  float r = fmaxf(d, 0.f);
  float e = __expf(fmaf(64.f * r, r, -C_OFF));  // junk when !pos&&!neg, unused
  s_p += pos ? e : 0.f;
  s_n += neg ? e : 0.f;
  nn += neg ? 1 : 0;
  const bool isc = neg && (s > CAND_THRESH);
  cc += isc ? 1 : 0;
  float v = isc ? s : NEG_INF;
  // branchless insert into sorted-desc c4[0..3] (7 min/max ops)
  float t = fmaxf(c4[3], v);
  c4[3] = fminf(c4[2], t);
  t = fmaxf(c4[2], t);
  c4[2] = fminf(c4[1], t);
  t = fmaxf(c4[1], t);
  c4[1] = fminf(c4[0], t);
  c4[0] = fmaxf(c4[0], t);
}

__global__ void __launch_bounds__(THREADS, 4) ranking_partial_kernel(
    const float* __restrict__ sim, const float* __restrict__ label,
    float* __restrict__ partials) {
  const int blk = blockIdx.x;
  const int row = blk >> 3;
  const int chunk = blk & 7;
  const int tid = threadIdx.x;
  const int wave = tid >> 6, lane = tid & 63;

  __shared__ float cand[CAP];
  __shared__ int cnt;
  __shared__ float ls_p[4], ls_n[4];
  __shared__ int ls_c[4], ls_cc[4], ls_ccmax[4];
  __shared__ float ltop[4][16];
  if (tid == 0) cnt = 0;
  __syncthreads();

  const size_t base4 = (size_t)row * (N / 4) + (size_t)chunk * (CHUNK_ELEMS / 4);
  const float4* sim4 = reinterpret_cast<const float4*>(sim) + base4;
  const float4* lab4 = reinterpret_cast<const float4*>(label) + base4;

  // ---- batch ALL loads up front: 16 dwordx4 in flight (needs ~64 VGPRs,
  // enabled by __launch_bounds__(256,4) -> 128-VGPR budget) ----
  float4 S[ITER], L[ITER];
#pragma unroll
  for (int it = 0; it < ITER; ++it) {
    S[it] = sim4[it * THREADS + tid];
    L[it] = lab4[it * THREADS + tid];
  }

  float s_p = 0.f, s_n = 0.f;
  int nn = 0, cc = 0;
  float c4[4] = {NEG_INF, NEG_INF, NEG_INF, NEG_INF};

#pragma unroll
  for (int it = 0; it < ITER; ++it) {
    proc(S[it].x, L[it].x, s_p, s_n, nn, cc, c4);
    proc(S[it].y, L[it].y, s_p, s_n, nn, cc, c4);
    proc(S[it].z, L[it].z, s_p, s_n, nn, cc, c4);
    proc(S[it].w, L[it].w, s_p, s_n, nn, cc, c4);
  }

  // ---- epilogue: compact candidates to LDS (rare, cheap) ----
  const int nst = min(cc, 4);
  for (int i = 0; i < nst; ++i) {
    int p = atomicAdd(&cnt, 1);
    if (p < CAP) cand[p] = c4[i];
  }

  float sw_p = wave_sum_f(s_p);
  float sw_n = wave_sum_f(s_n);
  int nw = wave_sum_i(nn);
  int ccw = wave_sum_i(cc);
  int ccmx = wave_max_i(cc);
  if (lane == 0) {
    ls_p[wave] = sw_p;
    ls_n[wave] = sw_n;
    ls_c[wave] = nw;
    ls_cc[wave] = ccw;
    ls_ccmax[wave] = ccmx;
  }
  __syncthreads();

  float sp_tot = ls_p[0] + ls_p[1] + ls_p[2] + ls_p[3];
  float sn_tot = ls_n[0] + ls_n[1] + ls_n[2] + ls_n[3];
  const int nn_tot = ls_c[0] + ls_c[1] + ls_c[2] + ls_c[3];
  const int cc_tot = ls_cc[0] + ls_cc[1] + ls_cc[2] + ls_cc[3];
  const int cc_max = max(max(ls_ccmax[0], ls_ccmax[1]), max(ls_ccmax[2], ls_ccmax[3]));

  // fallback needed if: a thread dropped candidates, LDS overflow, or the
  // candidate set provably may miss the chunk's top-10 negatives.
  const bool bad = (cc_max > 4) || (cc_tot > CAP) || (cc_tot < 10 && cc_tot < nn_tot);

  float t[16];
#pragma unroll
  for (int i = 0; i < 16; ++i) t[i] = NEG_INF;

  float* P = partials + (size_t)blk * PSTRIDE;

  if (!bad) {
    if (wave == 0) {
      const int c = cnt < CAP ? cnt : CAP;
      for (int i = lane; i < c; i += 64) insert10(t, cand[i]);
#pragma unroll
      for (int off = 1; off < 64; off <<= 1) merge_lists_shfl(t, off);
      if (lane == 0) {
        P[0] = sp_tot;
        P[1] = sn_tot;
        P[2] = (float)nn_tot;
        P[3] = 0.f;
#pragma unroll
        for (int i = 0; i < 10; ++i) P[4 + i] = t[i];
      }
    }
  } else {
    // exact rescan of this chunk (block-uniform branch; registers still hold data)
#pragma unroll
    for (int it = 0; it < ITER; ++it) {
      if (L[it].x < 0.25f) insert10(t, S[it].x);
      if (L[it].y < 0.25f) insert10(t, S[it].y);
      if (L[it].z < 0.25f) insert10(t, S[it].z);
      if (L[it].w < 0.25f) insert10(t, S[it].w);
    }
#pragma unroll
    for (int off = 1; off < 64; off <<= 1) merge_lists_shfl(t, off);
    if (lane == 0) {
#pragma unroll
      for (int i = 0; i < 16; ++i) ltop[wave][i] = t[i];
    }
    __syncthreads();
    if (wave == 0) {
      float m[16];
      if (lane < 4) {
#pragma unroll
        for (int i = 0; i < 16; ++i) m[i] = ltop[lane][i];
      } else {
#pragma unroll
        for (int i = 0; i < 16; ++i) m[i] = NEG_INF;
      }
      merge_lists_shfl(m, 1);
      merge_lists_shfl(m, 2);
      if (lane == 0) {
        P[0] = sp_tot;
        P[1] = sn_tot;
        P[2] = (float)nn_tot;
        P[3] = 0.f;
#pragma unroll
        for (int i = 0; i < 10; ++i) P[4 + i] = m[i];
      }
    }
  }
}

__global__ void __launch_bounds__(256) final_kernel(
    const float* __restrict__ partials, float* __restrict__ out) {
  const int r = threadIdx.x;  // one row per thread, 256 rows
  float sp = 0.f, sn = 0.f, nnf = 0.f;
  float t[16];
#pragma unroll
  for (int i = 0; i < 16; ++i) t[i] = NEG_INF;
#pragma unroll
  for (int c = 0; c < CHUNKS; ++c) {
    const float* P = partials + (size_t)(r * CHUNKS + c) * PSTRIDE;
    sp += P[0];
    sn += P[1];
    nnf += P[2];
#pragma unroll
    for (int i = 0; i < 10; ++i) insert10(t, P[4 + i]);
  }

  // any positives <=> sp > 0 (each pos term >= exp(-40.96) > 0)
  float lse_p = (sp > 0.f) ? (C_OFF + __logf(sp)) : 0.f;
  float lse_n_all = (sn > 0.f) ? (C_OFF + __logf(sn)) : NEG_INF;

  float mx = NEG_INF;
  float lg[10];
#pragma unroll
  for (int i = 0; i < 10; ++i) {
    float v = t[i];
    float a = fmaxf(v - 0.2f, 0.f);
    float lo = a * (v - 0.2f) * 64.f;
    lg[i] = lo;
    mx = fmaxf(mx, lo);
  }
  float ss = 0.f;
#pragma unroll
  for (int i = 0; i < 10; ++i) ss += __expf(lg[i] - mx);
  float lse_n_top = mx + __logf(ss);

  float lse_n = (nnf > 20.5f) ? lse_n_top : lse_n_all;
  float x = lse_n + lse_p;
  float loss = fmaxf(x, 0.f) + log1pf(__expf(-fabsf(x)));

  loss = wave_sum_f(loss);
  __shared__ float ws[4];
  if ((r & 63) == 0) ws[r >> 6] = loss;
  __syncthreads();
  if (r == 0) out[0] = (ws[0] + ws[1] + ws[2] + ws[3]) * (1.0f / 256.0f);
}

extern "C" void kernel_launch(void* const* d_in, const int* in_sizes, int n_in,
                              void* d_out, int out_size, void* d_ws, size_t ws_size,
                              hipStream_t stream) {
  const float* sim = (const float*)d_in[0];
  const float* label = (const float*)d_in[1];
  float* out = (float*)d_out;
  float* partials = (float*)d_ws;  // NBLOCKS * PSTRIDE floats = 128 KB
  ranking_partial_kernel<<<dim3(NBLOCKS), dim3(THREADS), 0, stream>>>(sim, label, partials);
  final_kernel<<<dim3(1), dim3(256), 0, stream>>>(partials, out);
}

// Round 5
// 157.612 us; speedup vs baseline: 1.0225x; 1.0225x over previous
//
#include <hip/hip_runtime.h>
#include <cmath>

#define NEG_INF (-1.0e30f)

static constexpr int B = 256;
static constexpr int N = 65536;
static constexpr int CHUNKS = 16;                       // blocks per row
static constexpr int THREADS = 256;                     // 4 waves per block
static constexpr int NBLOCKS = B * CHUNKS;              // 4096
static constexpr int CHUNK_ELEMS = N / CHUNKS;          // 4096
static constexpr int ITER = CHUNK_ELEMS / 4 / THREADS;  // 4 float4 per thread per array
static constexpr float C_OFF = 40.96f;                  // 64*0.8^2, upper bound of both logits
static constexpr float CAND_THRESH = 0.90f;             // mean ~102 candidates / 4096-elem chunk
static constexpr int CAP = 512;                         // LDS candidate capacity
// SoA partials in d_ws: [0]=sp [1]=sn [2]=nn [3..12]=top10, each stride NBLOCKS
static constexpr int NPART = 13;

__device__ __forceinline__ float wave_sum_f(float v) {
#pragma unroll
  for (int off = 32; off >= 1; off >>= 1) v += __shfl_xor(v, off, 64);
  return v;
}
__device__ __forceinline__ int wave_sum_i(int v) {
#pragma unroll
  for (int off = 32; off >= 1; off >>= 1) v += __shfl_xor(v, off, 64);
  return v;
}
__device__ __forceinline__ int wave_max_i(int v) {
#pragma unroll
  for (int off = 32; off >= 1; off >>= 1) v = max(v, __shfl_xor(v, off, 64));
  return v;
}

// sorted-descending top-10 insert into t[0..9] (t[10..15] pad)
__device__ __forceinline__ void insert10(float t[16], float s) {
  if (s > t[9]) {
    t[9] = s;
#pragma unroll
    for (int i = 9; i > 0; --i) {
      float a = t[i - 1], b = t[i];
      t[i - 1] = fmaxf(a, b);
      t[i] = fminf(a, b);
    }
  }
}

// Merge this lane's descending-sorted 16-list with XOR-partner lane's list,
// keeping top-16 of the union (bitonic top-k merge).
__device__ __forceinline__ void merge_lists_shfl(float t[16], int off) {
  float b[16];
#pragma unroll
  for (int i = 0; i < 16; ++i) b[i] = __shfl_xor(t[i], off, 64);
  float c[16];
#pragma unroll
  for (int i = 0; i < 16; ++i) c[i] = fmaxf(t[i], b[15 - i]);
#pragma unroll
  for (int s = 8; s >= 1; s >>= 1) {
#pragma unroll
    for (int i = 0; i < 16; ++i) {
      if ((i & s) == 0) {
        float lo = c[i], hi = c[i + s];
        c[i] = fmaxf(lo, hi);
        c[i + s] = fminf(lo, hi);
      }
    }
  }
#pragma unroll
  for (int i = 0; i < 16; ++i) t[i] = c[i];
}

// Hot-loop per element: fully branchless straight-line code.
__device__ __forceinline__ void proc(float s, float l, float& s_p, float& s_n,
                                     int& nn, int& cc, float c4[4]) {
  const bool pos = l > 0.5f;
  const bool neg = l < 0.25f;
  float d = pos ? (0.8f - s) : (s - 0.2f);
  float r = fmaxf(d, 0.f);
  float e = __expf(fmaf(64.f * r, r, -C_OFF));  // junk when !pos&&!neg, unused
  s_p += pos ? e : 0.f;
  s_n += neg ? e : 0.f;
  nn += neg ? 1 : 0;
  const bool isc = neg && (s > CAND_THRESH);
  cc += isc ? 1 : 0;
  float v = isc ? s : NEG_INF;
  // branchless insert into sorted-desc c4[0..3]
  float t = fmaxf(c4[3], v);
  c4[3] = fminf(c4[2], t);
  t = fmaxf(c4[2], t);
  c4[2] = fminf(c4[1], t);
  t = fmaxf(c4[1], t);
  c4[1] = fminf(c4[0], t);
  c4[0] = fmaxf(c4[0], t);
}

__global__ void __launch_bounds__(THREADS, 8) ranking_partial_kernel(
    const float* __restrict__ sim, const float* __restrict__ label,
    float* __restrict__ partials) {
  const int blk = blockIdx.x;
  const int row = blk >> 4;
  const int chunk = blk & 15;
  const int tid = threadIdx.x;
  const int wave = tid >> 6, lane = tid & 63;

  __shared__ float cand[CAP];
  __shared__ int cnt;
  __shared__ float ls_p[4], ls_n[4];
  __shared__ int ls_c[4], ls_cc[4], ls_ccmax[4];
  __shared__ float ltop[4][16];
  if (tid == 0) cnt = 0;
  __syncthreads();

  const size_t base4 = (size_t)row * (N / 4) + (size_t)chunk * (CHUNK_ELEMS / 4);
  const float4* sim4 = reinterpret_cast<const float4*>(sim) + base4;
  const float4* lab4 = reinterpret_cast<const float4*>(label) + base4;

  float4 S[ITER], L[ITER];
#pragma unroll
  for (int it = 0; it < ITER; ++it) {
    S[it] = sim4[it * THREADS + tid];
    L[it] = lab4[it * THREADS + tid];
  }

  float s_p = 0.f, s_n = 0.f;
  int nn = 0, cc = 0;
  float c4[4] = {NEG_INF, NEG_INF, NEG_INF, NEG_INF};

#pragma unroll
  for (int it = 0; it < ITER; ++it) {
    proc(S[it].x, L[it].x, s_p, s_n, nn, cc, c4);
    proc(S[it].y, L[it].y, s_p, s_n, nn, cc, c4);
    proc(S[it].z, L[it].z, s_p, s_n, nn, cc, c4);
    proc(S[it].w, L[it].w, s_p, s_n, nn, cc, c4);
  }

  // ---- epilogue: compact candidates to LDS (rare, cheap) ----
  const int nst = min(cc, 4);
  for (int i = 0; i < nst; ++i) {
    int p = atomicAdd(&cnt, 1);
    if (p < CAP) cand[p] = c4[i];
  }

  float sw_p = wave_sum_f(s_p);
  float sw_n = wave_sum_f(s_n);
  int nw = wave_sum_i(nn);
  int ccw = wave_sum_i(cc);
  int ccmx = wave_max_i(cc);
  if (lane == 0) {
    ls_p[wave] = sw_p;
    ls_n[wave] = sw_n;
    ls_c[wave] = nw;
    ls_cc[wave] = ccw;
    ls_ccmax[wave] = ccmx;
  }
  __syncthreads();

  float sp_tot = ls_p[0] + ls_p[1] + ls_p[2] + ls_p[3];
  float sn_tot = ls_n[0] + ls_n[1] + ls_n[2] + ls_n[3];
  const int nn_tot = ls_c[0] + ls_c[1] + ls_c[2] + ls_c[3];
  const int cc_tot = ls_cc[0] + ls_cc[1] + ls_cc[2] + ls_cc[3];
  const int cc_max = max(max(ls_ccmax[0], ls_ccmax[1]), max(ls_ccmax[2], ls_ccmax[3]));

  // fallback needed if: a thread dropped candidates, LDS overflow, or the
  // candidate set provably may miss the chunk's top-10 negatives.
  const bool bad = (cc_max > 4) || (cc_tot > CAP) || (cc_tot < 10 && cc_tot < nn_tot);

  float t[16];
#pragma unroll
  for (int i = 0; i < 16; ++i) t[i] = NEG_INF;

  if (!bad) {
    if (wave == 0) {
      const int c = cnt < CAP ? cnt : CAP;
      for (int i = lane; i < c; i += 64) insert10(t, cand[i]);
#pragma unroll
      for (int off = 1; off < 64; off <<= 1) merge_lists_shfl(t, off);
      if (lane == 0) {
        partials[0 * NBLOCKS + blk] = sp_tot;
        partials[1 * NBLOCKS + blk] = sn_tot;
        partials[2 * NBLOCKS + blk] = (float)nn_tot;
#pragma unroll
        for (int i = 0; i < 10; ++i) partials[(3 + i) * NBLOCKS + blk] = t[i];
      }
    }
  } else {
    // exact rescan of this chunk (block-uniform branch; registers still hold data)
#pragma unroll
    for (int it = 0; it < ITER; ++it) {
      if (L[it].x < 0.25f) insert10(t, S[it].x);
      if (L[it].y < 0.25f) insert10(t, S[it].y);
      if (L[it].z < 0.25f) insert10(t, S[it].z);
      if (L[it].w < 0.25f) insert10(t, S[it].w);
    }
#pragma unroll
    for (int off = 1; off < 64; off <<= 1) merge_lists_shfl(t, off);
    if (lane == 0) {
#pragma unroll
      for (int i = 0; i < 16; ++i) ltop[wave][i] = t[i];
    }
    __syncthreads();
    if (wave == 0) {
      float m[16];
      if (lane < 4) {
#pragma unroll
        for (int i = 0; i < 16; ++i) m[i] = ltop[lane][i];
      } else {
#pragma unroll
        for (int i = 0; i < 16; ++i) m[i] = NEG_INF;
      }
      merge_lists_shfl(m, 1);
      merge_lists_shfl(m, 2);
      if (lane == 0) {
        partials[0 * NBLOCKS + blk] = sp_tot;
        partials[1 * NBLOCKS + blk] = sn_tot;
        partials[2 * NBLOCKS + blk] = (float)nn_tot;
#pragma unroll
        for (int i = 0; i < 10; ++i) partials[(3 + i) * NBLOCKS + blk] = m[i];
      }
    }
  }
}

// One wave per row: merge the row's 16 chunk-partials, compute the row loss.
__global__ void __launch_bounds__(64) row_kernel(
    const float* __restrict__ partials, float* __restrict__ row_loss) {
  const int row = blockIdx.x;
  const int lane = threadIdx.x;
  const bool act = lane < CHUNKS;
  const int blk = row * CHUNKS + (act ? lane : 0);

  float sp = act ? partials[0 * NBLOCKS + blk] : 0.f;
  float sn = act ? partials[1 * NBLOCKS + blk] : 0.f;
  float nnf = act ? partials[2 * NBLOCKS + blk] : 0.f;
  float t[16];
#pragma unroll
  for (int i = 0; i < 10; ++i)
    t[i] = act ? partials[(3 + i) * NBLOCKS + blk] : NEG_INF;
#pragma unroll
  for (int i = 10; i < 16; ++i) t[i] = NEG_INF;

  sp = wave_sum_f(sp);
  sn = wave_sum_f(sn);
  nnf = wave_sum_f(nnf);
  // merge top-10 lists across the 16 chunk-lanes
  merge_lists_shfl(t, 1);
  merge_lists_shfl(t, 2);
  merge_lists_shfl(t, 4);
  merge_lists_shfl(t, 8);

  if (lane == 0) {
    // any positives <=> sp > 0 (each pos term >= exp(-40.96) > 0)
    float lse_p = (sp > 0.f) ? (C_OFF + __logf(sp)) : 0.f;
    float lse_n_all = (sn > 0.f) ? (C_OFF + __logf(sn)) : NEG_INF;

    float mx = NEG_INF;
    float lg[10];
#pragma unroll
    for (int i = 0; i < 10; ++i) {
      float v = t[i];
      float a = fmaxf(v - 0.2f, 0.f);
      float lo = a * (v - 0.2f) * 64.f;
      lg[i] = lo;
      mx = fmaxf(mx, lo);
    }
    float ss = 0.f;
#pragma unroll
    for (int i = 0; i < 10; ++i) ss += __expf(lg[i] - mx);
    float lse_n_top = mx + __logf(ss);

    float lse_n = (nnf > 20.5f) ? lse_n_top : lse_n_all;
    float x = lse_n + lse_p;
    float loss = fmaxf(x, 0.f) + log1pf(__expf(-fabsf(x)));
    row_loss[row] = loss;
  }
}

__global__ void __launch_bounds__(256) final_kernel(
    const float* __restrict__ row_loss, float* __restrict__ out) {
  const int tid = threadIdx.x;
  float v = row_loss[tid];
  v = wave_sum_f(v);
  __shared__ float ws[4];
  if ((tid & 63) == 0) ws[tid >> 6] = v;
  __syncthreads();
  if (tid == 0) out[0] = (ws[0] + ws[1] + ws[2] + ws[3]) * (1.0f / 256.0f);
}

extern "C" void kernel_launch(void* const* d_in, const int* in_sizes, int n_in,
                              void* d_out, int out_size, void* d_ws, size_t ws_size,
                              hipStream_t stream) {
  const float* sim = (const float*)d_in[0];
  const float* label = (const float*)d_in[1];
  float* out = (float*)d_out;
  float* partials = (float*)d_ws;                 // NPART * NBLOCKS floats = 208 KB
  float* rows = partials + NPART * NBLOCKS;       // + 256 floats
  ranking_partial_kernel<<<dim3(NBLOCKS), dim3(THREADS), 0, stream>>>(sim, label, partials);
  row_kernel<<<dim3(B), dim3(64), 0, stream>>>(partials, rows);
  final_kernel<<<dim3(1), dim3(256), 0, stream>>>(rows, out);
}